// Round 4
// baseline (140.768 us; speedup 1.0000x reference)
//
#include <hip/hip_runtime.h>
#include <cmath>

#define FIN 256
#define FQK 256
#define SCALING 0.0625f  // FQK^-0.5 = 1/16
#define MAX_SEG 256
#define ASTRIDE 264      // bf16 elems per LDS row: 528 B (b128-aligned, benign banking)

typedef __bf16 bf16_t;
typedef bf16_t bf16x8 __attribute__((ext_vector_type(8)));
typedef float  f32x4  __attribute__((ext_vector_type(4)));
typedef float  f32x2  __attribute__((ext_vector_type(2)));

__device__ __forceinline__ unsigned short f2bf(float f) {
    unsigned int u = __float_as_uint(f);
    u += 0x7FFFu + ((u >> 16) & 1u);   // RNE
    return (unsigned short)(u >> 16);
}
__device__ __forceinline__ float bf_lo(unsigned int w) { return __uint_as_float(w << 16); }
__device__ __forceinline__ float bf_hi(unsigned int w) { return __uint_as_float(w & 0xFFFF0000u); }

// native cast is RNE on gfx950 -> v_cvt_pk_bf16_f32 pairs (compiler-formed)
__device__ __forceinline__ bf16x8 cvt8(float4 a, float4 b) {
    bf16x8 r;
    r[0] = (bf16_t)a.x; r[1] = (bf16_t)a.y; r[2] = (bf16_t)a.z; r[3] = (bf16_t)a.w;
    r[4] = (bf16_t)b.x; r[5] = (bf16_t)b.y; r[6] = (bf16_t)b.z; r[7] = (bf16_t)b.w;
    return r;
}

// ---------------------------------------------------------------------------
// Kernel 1 (fused): blocks [0,FIN): MbF (B-fragment-swizzled M matrix)
//   M[f][k] = SCALING * sum_c W[c][f] * W[256+c][k], stored so the gemm's
//   B-fragment load is coalesced.
// blocks [FIN, FIN+segBlocks): seg[n] = lower_bound(src, n).
// ---------------------------------------------------------------------------
__global__ __launch_bounds__(256) void m_seg_kernel(const float* __restrict__ W,
                                                    unsigned short* __restrict__ MbF,
                                                    const int* __restrict__ src,
                                                    int* __restrict__ seg, int N, int E) {
    const int b = blockIdx.x;
    if (b < FIN) {
        const int f = b;
        const int k = threadIdx.x;
        const float* __restrict__ Wq = W;              // block-uniform loads
        const float* __restrict__ Wk = W + FQK * FIN;  // coalesced loads
        float acc = 0.f;
#pragma unroll 8
        for (int c = 0; c < FQK; ++c)
            acc += Wq[c * FIN + f] * Wk[c * FIN + k];
        const int ft  = f >> 4, m16 = f & 15;
        const int kcI = k >> 5, q = (k >> 3) & 3, e = k & 7;
        MbF[(size_t)(((kcI * 16 + ft) * 64 + q * 16 + m16) * 8 + e)] = f2bf(acc * SCALING);
    } else {
        const int n = (b - FIN) * 256 + threadIdx.x;
        if (n > N) return;
        int lo = 0, hi = E;
        while (lo < hi) {
            const int mid = (lo + hi) >> 1;
            if (src[mid] < n) lo = mid + 1; else hi = mid;
        }
        seg[n] = lo;
    }
}

// ---------------------------------------------------------------------------
// Kernel 2: y[n][f] = sum_k x[n][k] * M[f][k], bf16 MFMA (16x16x32).
// 32 rows/block, 4 waves split f into 64-wide slices.
// Stage: pass-based mapping, fully coalesced 32B/thread reads from x.
// Epilogue: acc -> LDS (bf16) -> row-major readback -> 4x uint4 coalesced
// stores per thread (replaces 32 scattered 2B stores).
// ---------------------------------------------------------------------------
__global__ __launch_bounds__(256) void gemm_y_kernel(const float* __restrict__ x,
                                                     const unsigned short* __restrict__ MbF,
                                                     unsigned short* __restrict__ y, int N) {
    __shared__ unsigned short sA[32 * ASTRIDE];

    const int t    = threadIdx.x;
    const int wv   = t >> 6;
    const int lane = t & 63;
    const int q    = lane >> 4;    // quad 0..3 -> k-offset q*8
    const int m16  = lane & 15;
    const int n0   = blockIdx.x * 32;
    const int f0   = wv * 64;

    // ---- stage A (coalesced): pass p -> row p*8 + (t>>5), cols (t&31)*8..+8
    {
        const int rsub = t >> 5;          // 0..7
        const int col  = (t & 31) * 8;
#pragma unroll
        for (int p = 0; p < 4; ++p) {
            const int r  = p * 8 + rsub;
            const int n  = n0 + r;
            const int nc = n < N ? n : N - 1;      // clamp; bad rows never stored
            const float* __restrict__ xp = x + (size_t)nc * FIN + col;
            const float4 a = *(const float4*)(xp);
            const float4 b = *(const float4*)(xp + 4);
            *(bf16x8*)&sA[r * ASTRIDE + col] = cvt8(a, b);
        }
    }
    __syncthreads();

    f32x4 acc[2][4] = {};   // [m-tile][f-tile]

#pragma unroll
    for (int kc = 0; kc < FIN; kc += 32) {
        bf16x8 afrag[2];
#pragma unroll
        for (int mt = 0; mt < 2; ++mt)
            afrag[mt] = *(const bf16x8*)&sA[(mt * 16 + m16) * ASTRIDE + kc + q * 8];

        const unsigned short* __restrict__ bp =
            MbF + (size_t)(((kc >> 5) * 16 + (f0 >> 4)) * 64 + lane) * 8;
#pragma unroll
        for (int ft = 0; ft < 4; ++ft) {
            union { uint4 u; bf16x8 v; } bu;
            bu.u = *(const uint4*)(bp + ft * 512);
#pragma unroll
            for (int mt = 0; mt < 2; ++mt)
                acc[mt][ft] = __builtin_amdgcn_mfma_f32_16x16x32_bf16(afrag[mt], bu.v,
                                                                     acc[mt][ft], 0, 0, 0);
        }
    }

    // ---- epilogue: transpose through LDS for packed stores
    __syncthreads();   // all A-reads done; safe to overwrite sA
#pragma unroll
    for (int mt = 0; mt < 2; ++mt)
#pragma unroll
        for (int r = 0; r < 4; ++r)
#pragma unroll
            for (int ft = 0; ft < 4; ++ft)
                sA[(mt * 16 + q * 4 + r) * ASTRIDE + f0 + ft * 16 + m16] =
                    f2bf(acc[mt][ft][r]);
    __syncthreads();

#pragma unroll
    for (int s = 0; s < 4; ++s) {
        const int row = s * 8 + (t >> 5);
        const int c16 = t & 31;
        const int n   = n0 + row;
        if (n < N) {
            const uint4 v = *(const uint4*)&sA[row * ASTRIDE + c16 * 8];
            *(uint4*)(y + (size_t)n * FIN + c16 * 8) = v;
        }
    }
}

// ---------------------------------------------------------------------------
// Kernel 3: one wave per node, 8-lane groups (g=edge slot, j=64B row slice).
// 3 gather stages in flight, loop unrolled x3 (zero-copy buffer rotation);
// dest prefetched one stage ahead of its gathers. No block barrier (exlds is
// per-wave). Dot in f32x2 (v_pk_fma_f32 candidate).
// All gathered indices clamped to [0,N): rocprof counter-replay re-poisons
// inputs, and unclamped garbage dest values would read arbitrary addresses.
// ---------------------------------------------------------------------------
__device__ __forceinline__ f32x2 dotp(unsigned int wq, float xl, float xh, f32x2 acc) {
    f32x2 e;  e[0] = bf_lo(wq); e[1] = bf_hi(wq);
    f32x2 xx; xx[0] = xl;       xx[1] = xh;
    return __builtin_elementwise_fma(e, xx, acc);
}
__device__ __forceinline__ f32x2 dot8v(uint4 qv, float4 xa, float4 xb, f32x2 acc) {
    acc = dotp(qv.x, xa.x, xa.y, acc);
    acc = dotp(qv.y, xa.z, xa.w, acc);
    acc = dotp(qv.z, xb.x, xb.y, acc);
    acc = dotp(qv.w, xb.z, xb.w, acc);
    return acc;
}

__global__ __launch_bounds__(256) void node_edge_kernel(const float* __restrict__ x,
                                                        const unsigned short* __restrict__ y,
                                                        const int* __restrict__ dest,
                                                        const int* __restrict__ seg,
                                                        float* __restrict__ out, int N) {
    __shared__ float exlds[4][MAX_SEG];

    const int w    = threadIdx.x >> 6;
    const int lane = threadIdx.x & 63;
    const int n    = blockIdx.x * 4 + w;
    const int g    = lane >> 3;    // edge slot 0..7
    const int j    = lane & 7;     // 64B slice of the row

    if (n >= N) return;
    const int s0  = seg[n];
    const int cnt = seg[n + 1] - s0;
    if (cnt <= 0) return;

    // x[n] slice for this lane: k = j*32 .. +32 (fp32, exact)
    float4 xf[8];
    {
        const float* __restrict__ xr = x + (size_t)n * FIN + j * 32;
#pragma unroll
        for (int u = 0; u < 8; ++u) xf[u] = *(const float4*)(xr + u * 4);
    }

    float sum = 0.f;

    // clamp gathered index against replay-poisoned dest values
#define DCLAMP(d) ((unsigned)(d) < (unsigned)N ? (d) : 0)

#define GISSUE(B0, B1, B2, B3, d, valid)                                       \
    if (valid) {                                                               \
        const uint4* __restrict__ yr =                                         \
            (const uint4*)(y + (size_t)DCLAMP(d) * FIN) + j * 4;               \
        B0 = yr[0]; B1 = yr[1]; B2 = yr[2]; B3 = yr[3];                        \
    }

#define CONSUME(B0, B1, B2, B3, idx, valid)                                    \
    if (valid) {                                                               \
        f32x2 a2 = {0.f, 0.f};                                                 \
        a2 = dot8v(B0, xf[0], xf[1], a2);                                      \
        a2 = dot8v(B1, xf[2], xf[3], a2);                                      \
        a2 = dot8v(B2, xf[4], xf[5], a2);                                      \
        a2 = dot8v(B3, xf[6], xf[7], a2);                                      \
        float accv = a2[0] + a2[1];                                            \
        accv += __shfl_xor(accv, 1, 64);                                       \
        accv += __shfl_xor(accv, 2, 64);                                       \
        accv += __shfl_xor(accv, 4, 64);                                       \
        const float ex = __expf(accv);                                         \
        sum += ex;                                                             \
        if (j == 0 && (idx) < MAX_SEG) exlds[w][idx] = ex;                     \
    }

    uint4 A0 = {}, A1 = {}, A2 = {}, A3 = {};
    uint4 B0 = {}, B1 = {}, B2 = {}, B3 = {};
    uint4 C0 = {}, C1 = {}, C2 = {}, C3 = {};

    int  iA = g, iB = g + 8, iC = g + 16;
    bool vA = iA < cnt, vB = iB < cnt, vC = iC < cnt;

    {   // prologue: 3 stages in flight
        const int dA = vA ? dest[s0 + iA] : 0;
        GISSUE(A0, A1, A2, A3, dA, vA);
        const int dB = vB ? dest[s0 + iB] : 0;
        GISSUE(B0, B1, B2, B3, dB, vB);
        const int dC = vC ? dest[s0 + iC] : 0;
        GISSUE(C0, C1, C2, C3, dC, vC);
    }
    int inext = g + 24;                              // stage it+3 index
    int dN    = (inext < cnt) ? dest[s0 + inext] : 0;

    const int nit = (cnt + 7) >> 3;
    for (int it = 0; it < nit; it += 3) {
        // phase A: consume stage it, reuse A for stage it+3
        CONSUME(A0, A1, A2, A3, iA, vA);
        iA = inext; vA = iA < cnt;
        GISSUE(A0, A1, A2, A3, dN, vA);
        inext += 8; dN = (inext < cnt) ? dest[s0 + inext] : 0;
        // phase B
        CONSUME(B0, B1, B2, B3, iB, vB);
        iB = inext; vB = iB < cnt;
        GISSUE(B0, B1, B2, B3, dN, vB);
        inext += 8; dN = (inext < cnt) ? dest[s0 + inext] : 0;
        // phase C
        CONSUME(C0, C1, C2, C3, iC, vC);
        iC = inext; vC = iC < cnt;
        GISSUE(C0, C1, C2, C3, dN, vC);
        inext += 8; dN = (inext < cnt) ? dest[s0 + inext] : 0;
    }

    // 8 groups hold identical partial sums internally; combine groups
    sum += __shfl_xor(sum, 8, 64);
    sum += __shfl_xor(sum, 16, 64);
    sum += __shfl_xor(sum, 32, 64);
    const float inv = 1.0f / sum;

    const int lim = cnt < MAX_SEG ? cnt : MAX_SEG;
    for (int i = lane; i < lim; i += 64)
        out[s0 + i] = exlds[w][i] * inv;

#undef GISSUE
#undef CONSUME
#undef DCLAMP
}

// ---------------------------------------------------------------------------
extern "C" void kernel_launch(void* const* d_in, const int* in_sizes, int n_in,
                              void* d_out, int out_size, void* d_ws, size_t ws_size,
                              hipStream_t stream) {
    const float* x  = (const float*)d_in[0];
    const int*   ei = (const int*)d_in[1];
    const float* W  = (const float*)d_in[2];
    float* out = (float*)d_out;

    const int N = in_sizes[0] / FIN;
    const int E = in_sizes[1] / 2;

    // workspace layout
    unsigned short* MbF = (unsigned short*)d_ws;                // 256*256 bf16 (swizzled)
    unsigned short* y   = MbF + (size_t)FIN * FIN;              // N*256 bf16
    int*            seg = (int*)(y + (size_t)N * FIN);          // N+1

    const int segBlocks = (N + 256) / 256;                      // covers n = 0..N
    m_seg_kernel<<<FIN + segBlocks, 256, 0, stream>>>(W, MbF, ei, seg, N, E);

    gemm_y_kernel<<<(N + 31) / 32, 256, 0, stream>>>(x, MbF, y, N);

    node_edge_kernel<<<(N + 3) / 4, 256, 0, stream>>>(x, y, ei + E, seg, out, N);
}

// Round 5
// 132.784 us; speedup vs baseline: 1.0601x; 1.0601x over previous
//
#include <hip/hip_runtime.h>
#include <cmath>

#define FIN 256
#define FQK 256
#define SCALING 0.0625f  // FQK^-0.5 = 1/16
#define MAX_SEG 256
#define ASTRIDE 264      // f16 elems per LDS row: 528 B (b128-aligned, 2-way banks max)

typedef _Float16 f16_t;
typedef f16_t f16x8 __attribute__((ext_vector_type(8)));
typedef f16_t f16x2 __attribute__((ext_vector_type(2)));
typedef float f32x4 __attribute__((ext_vector_type(4)));

// fp32 -> fp16x8 (RNE via native cast)
__device__ __forceinline__ f16x8 cvt8h(float4 a, float4 b) {
    f16x8 r;
    r[0] = (f16_t)a.x; r[1] = (f16_t)a.y; r[2] = (f16_t)a.z; r[3] = (f16_t)a.w;
    r[4] = (f16_t)b.x; r[5] = (f16_t)b.y; r[6] = (f16_t)b.z; r[7] = (f16_t)b.w;
    return r;
}

// v_dot2_f32_f16 when available; exact scalar fallback otherwise
__device__ __forceinline__ float fdot2f(f16x2 a, f16x2 b, float c) {
#if __has_builtin(__builtin_amdgcn_fdot2)
    return __builtin_amdgcn_fdot2(a, b, c, false);
#else
    return c + (float)a[0] * (float)b[0] + (float)a[1] * (float)b[1];
#endif
}

union H16 { uint4 u; f16x2 h[4]; };
__device__ __forceinline__ float dot16(uint4 ya, uint4 xa, float acc) {
    H16 A; A.u = ya;
    H16 X; X.u = xa;
#pragma unroll
    for (int i = 0; i < 4; ++i) acc = fdot2f(A.h[i], X.h[i], acc);
    return acc;
}

// ---------------------------------------------------------------------------
// Kernel 1 (fused): blocks [0,FIN): MbF (B-fragment-swizzled M matrix, fp16)
//   M[f][k] = SCALING * sum_c W[c][f] * W[256+c][k]
//   flat = (((k>>5)*16 + (f>>4))*64 + ((k>>3)&3)*16 + (f&15))*8 + (k&7)
// blocks [FIN, FIN+segBlocks): seg[n] = lower_bound(src, n).
// ---------------------------------------------------------------------------
__global__ __launch_bounds__(256) void m_seg_kernel(const float* __restrict__ W,
                                                    f16_t* __restrict__ MbF,
                                                    const int* __restrict__ src,
                                                    int* __restrict__ seg, int N, int E) {
    const int b = blockIdx.x;
    if (b < FIN) {
        const int f = b;
        const int k = threadIdx.x;
        const float* __restrict__ Wq = W;              // block-uniform loads
        const float* __restrict__ Wk = W + FQK * FIN;  // coalesced loads
        float acc = 0.f;
#pragma unroll 8
        for (int c = 0; c < FQK; ++c)
            acc += Wq[c * FIN + f] * Wk[c * FIN + k];
        const int ft  = f >> 4, m16 = f & 15;
        const int kcI = k >> 5, q = (k >> 3) & 3, e = k & 7;
        MbF[(size_t)(((kcI * 16 + ft) * 64 + q * 16 + m16) * 8 + e)] =
            (f16_t)(acc * SCALING);
    } else {
        const int n = (b - FIN) * 256 + threadIdx.x;
        if (n > N) return;
        int lo = 0, hi = E;
        while (lo < hi) {
            const int mid = (lo + hi) >> 1;
            if (src[mid] < n) lo = mid + 1; else hi = mid;
        }
        seg[n] = lo;
    }
}

// ---------------------------------------------------------------------------
// Kernel 2: y[n][f] = sum_k x[n][k] * M[f][k], fp16 MFMA (16x16x32).
// 16 rows/block -> 1251 blocks (4.9/CU; was 2.4 with 32-row tiles).
// Stage writes BOTH sA (LDS) and xh (global fp16 copy of x, coalesced) from
// the same registers. B-fragments coalesced from swizzled MbF (L2-hot).
// Epilogue: acc -> LDS fp16 -> row-major readback -> 2x uint4 stores/thread.
// ---------------------------------------------------------------------------
__global__ __launch_bounds__(256) void gemm_y_kernel(const float* __restrict__ x,
                                                     const f16_t* __restrict__ MbF,
                                                     f16_t* __restrict__ y,
                                                     f16_t* __restrict__ xh, int N) {
    __shared__ f16_t sA[16 * ASTRIDE];

    const int t    = threadIdx.x;
    const int wv   = t >> 6;
    const int lane = t & 63;
    const int q    = lane >> 4;    // quad 0..3 -> k-offset q*8
    const int m16  = lane & 15;
    const int n0   = blockIdx.x * 16;
    const int f0   = wv * 64;

    // ---- stage A + xh: pass p -> row p*8 + (t>>5), cols (t&31)*8..+8
    {
        const int rsub = t >> 5;          // 0..7
        const int col  = (t & 31) * 8;
#pragma unroll
        for (int p = 0; p < 2; ++p) {
            const int r  = p * 8 + rsub;
            const int n  = n0 + r;
            const int nc = n < N ? n : N - 1;
            const float* __restrict__ xp = x + (size_t)nc * FIN + col;
            const float4 a = *(const float4*)(xp);
            const float4 b = *(const float4*)(xp + 4);
            const f16x8 v = cvt8h(a, b);
            *(f16x8*)&sA[r * ASTRIDE + col] = v;
            if (n < N) *(f16x8*)(xh + (size_t)n * FIN + col) = v;
        }
    }
    __syncthreads();

    f32x4 acc[4] = {};   // [f-tile]

#pragma unroll
    for (int kc = 0; kc < FIN; kc += 32) {
        const f16x8 af = *(const f16x8*)&sA[m16 * ASTRIDE + kc + q * 8];
        const f16_t* __restrict__ bp =
            MbF + (size_t)(((kc >> 5) * 16 + (f0 >> 4)) * 64 + lane) * 8;
#pragma unroll
        for (int ft = 0; ft < 4; ++ft) {
            union { uint4 u; f16x8 v; } bu;
            bu.u = *(const uint4*)(bp + ft * 512);
            acc[ft] = __builtin_amdgcn_mfma_f32_16x16x32_f16(af, bu.v, acc[ft], 0, 0, 0);
        }
    }

    // ---- epilogue: transpose through LDS for packed stores
    __syncthreads();   // all A-reads done; safe to overwrite sA
#pragma unroll
    for (int ft = 0; ft < 4; ++ft)
#pragma unroll
        for (int r = 0; r < 4; ++r)
            sA[(q * 4 + r) * ASTRIDE + f0 + ft * 16 + m16] = (f16_t)acc[ft][r];
    __syncthreads();

    {
        const int row = t >> 4;           // 0..15
        const int c   = (t & 15) * 16;    // f16-element col
        const int n   = n0 + row;
        if (n < N) {
            const uint4 v0 = *(const uint4*)&sA[row * ASTRIDE + c];
            const uint4 v1 = *(const uint4*)&sA[row * ASTRIDE + c + 8];
            *(uint4*)(y + (size_t)n * FIN + c)     = v0;
            *(uint4*)(y + (size_t)n * FIN + c + 8) = v1;
        }
    }
}

// ---------------------------------------------------------------------------
// Kernel 3: persistent waves (1024 blocks x 4 waves, each grid-strides over
// nodes). 8-lane groups (g=edge slot, j=64B slice); 2-deep pipeline, x2
// unrolled (zero-copy rotation). fp16 both sides -> fdot2 dot (16 instrs vs
// 48 for bf16 unpack+fma). All gathered indices clamped (replay poison).
// ---------------------------------------------------------------------------
__global__ __launch_bounds__(256) void node_edge_kernel(const f16_t* __restrict__ xh,
                                                        const f16_t* __restrict__ y,
                                                        const int* __restrict__ dest,
                                                        const int* __restrict__ seg,
                                                        float* __restrict__ out,
                                                        int N, int E, int nwaves) {
    __shared__ float exlds[4][MAX_SEG];

    const int w    = threadIdx.x >> 6;
    const int lane = threadIdx.x & 63;
    const int g    = lane >> 3;    // edge slot 0..7
    const int j    = lane & 7;     // 64B slice of the row

#define DCLAMP(d) ((unsigned)(d) < (unsigned)N ? (d) : 0)

#define GISSUE(B0, B1, B2, B3, i, valid)                                       \
    if (valid) {                                                               \
        const int d_ = DCLAMP(dest[s0 + (i)]);                                 \
        const uint4* __restrict__ yr = (const uint4*)(y + (size_t)d_ * FIN) + j * 4; \
        B0 = yr[0]; B1 = yr[1]; B2 = yr[2]; B3 = yr[3];                        \
    }

#define CONSUME(B0, B1, B2, B3, idx, valid)                                    \
    if (valid) {                                                               \
        float a_ = 0.f;                                                        \
        a_ = dot16(B0, X0, a_);                                                \
        a_ = dot16(B1, X1, a_);                                                \
        a_ = dot16(B2, X2, a_);                                                \
        a_ = dot16(B3, X3, a_);                                                \
        a_ += __shfl_xor(a_, 1, 64);                                           \
        a_ += __shfl_xor(a_, 2, 64);                                           \
        a_ += __shfl_xor(a_, 4, 64);                                           \
        const float ex = __expf(a_);                                           \
        sum += ex;                                                             \
        if (j == 0 && (idx) < MAX_SEG) exlds[w][idx] = ex;                     \
    }

    for (int n = blockIdx.x * 4 + w; n < N; n += nwaves) {
        int s0 = seg[n], s1 = seg[n + 1];
        s0 = min(max(s0, 0), E);                     // replay-poison clamps
        s1 = min(max(s1, 0), E);
        const int cnt = s1 - s0;
        if (cnt <= 0) continue;

        // xh[n] slice for this lane: elements j*32 .. +32 (fp16)
        const uint4* __restrict__ xp = (const uint4*)(xh + (size_t)n * FIN + j * 32);
        const uint4 X0 = xp[0], X1 = xp[1], X2 = xp[2], X3 = xp[3];

        float sum = 0.f;
        const int nit = (cnt + 7) >> 3;

        uint4 A0, A1, A2, A3, B0, B1, B2, B3;
        bool vA = g < cnt;
        GISSUE(A0, A1, A2, A3, g, vA);               // stage 0

        for (int it = 0; it < nit; it += 2) {
            const int iB = (it + 1) * 8 + g;         // stage it+1
            const bool vB = iB < cnt;
            GISSUE(B0, B1, B2, B3, iB, vB);
            CONSUME(A0, A1, A2, A3, it * 8 + g, vA);
            const int iA = (it + 2) * 8 + g;         // stage it+2
            vA = iA < cnt;
            GISSUE(A0, A1, A2, A3, iA, vA);
            CONSUME(B0, B1, B2, B3, iB, vB);
        }

        // 8 groups hold identical partial sums internally; combine groups
        sum += __shfl_xor(sum, 8, 64);
        sum += __shfl_xor(sum, 16, 64);
        sum += __shfl_xor(sum, 32, 64);
        const float inv = 1.0f / sum;

        const int lim = cnt < MAX_SEG ? cnt : MAX_SEG;
        for (int i = lane; i < lim; i += 64)
            out[s0 + i] = exlds[w][i] * inv;
    }

#undef GISSUE
#undef CONSUME
#undef DCLAMP
}

// ---------------------------------------------------------------------------
extern "C" void kernel_launch(void* const* d_in, const int* in_sizes, int n_in,
                              void* d_out, int out_size, void* d_ws, size_t ws_size,
                              hipStream_t stream) {
    const float* x  = (const float*)d_in[0];
    const int*   ei = (const int*)d_in[1];
    const float* W  = (const float*)d_in[2];
    float* out = (float*)d_out;

    const int N = in_sizes[0] / FIN;
    const int E = in_sizes[1] / 2;

    // workspace layout (all fp16 tables 16B-aligned)
    f16_t* MbF = (f16_t*)d_ws;                        // 256*256 fp16 (swizzled)
    f16_t* y   = MbF + (size_t)FIN * FIN;             // N*256 fp16
    f16_t* xh  = y + (size_t)N * FIN;                 // N*256 fp16
    int*   seg = (int*)(xh + (size_t)N * FIN);        // N+1

    const int segBlocks = (N + 256) / 256;            // covers n = 0..N
    m_seg_kernel<<<FIN + segBlocks, 256, 0, stream>>>(W, MbF, ei, seg, N, E);

    gemm_y_kernel<<<(N + 15) / 16, 256, 0, stream>>>(x, MbF, y, xh, N);

    const int neBlocks = 1024;
    node_edge_kernel<<<neBlocks, 256, 0, stream>>>(xh, y, ei + E, seg, out,
                                                   N, E, neBlocks * 4);
}